// Round 2
// baseline (527.786 us; speedup 1.0000x reference)
//
#include <hip/hip_runtime.h>

typedef unsigned int u32;
typedef unsigned short u16;
typedef unsigned long long u64;

typedef __bf16 bf16x8 __attribute__((ext_vector_type(8)));
typedef float f32x4 __attribute__((ext_vector_type(4)));

#define DEV __device__ __forceinline__

// ---------- helpers ----------
DEV u16 f2bf(float f) {            // RNE float -> bf16
  u32 u = __float_as_uint(f);
  u += 0x7fffu + ((u >> 16) & 1u);
  return (u16)(u >> 16);
}
DEV float bf2f(u16 u) { return __uint_as_float((u32)u << 16); }

DEV void gld_lds16(const void* g, void* l) {
  __builtin_amdgcn_global_load_lds((const __attribute__((address_space(1))) u32*)g,
                                   (__attribute__((address_space(3))) u32*)l, 16, 0, 0);
}

// monotone (value, lower-index-wins) packed sort key
DEV u64 packkey(float f, u32 idx) {
  u32 u = __float_as_uint(f);
  u = (u & 0x80000000u) ? ~u : (u | 0x80000000u);
  return ((u64)u << 32) | (u32)(~idx);
}

// ---------- hidden -> bf16 + column partial sums (float4, 512 blocks) ----------
__global__ __launch_bounds__(256) void k_conv_mean(const float4* __restrict__ hidden4,
                                                   ushort4* __restrict__ hb4,
                                                   float4* __restrict__ partial4) {
  const int c4 = blockIdx.x * 256 + threadIdx.x;   // 0..511
  const int r0 = blockIdx.y * 64;                  // 256 row-chunks
  float4 s = {0.f, 0.f, 0.f, 0.f};
  for (int r = 0; r < 64; r++) {
    float4 v = hidden4[(size_t)(r0 + r) * 512 + c4];
    ushort4 o; o.x = f2bf(v.x); o.y = f2bf(v.y); o.z = f2bf(v.z); o.w = f2bf(v.w);
    hb4[(size_t)(r0 + r) * 512 + c4] = o;
    s.x += v.x; s.y += v.y; s.z += v.z; s.w += v.w;
  }
  partial4[blockIdx.y * 512 + c4] = s;
}

// reduce 256 chunks -> mean (128 blocks, 16 cols each, 16-way split per col)
__global__ __launch_bounds__(256) void k_mean(const float* __restrict__ partial,
                                              float* __restrict__ mean) {
  __shared__ float red[256];
  const int t = threadIdx.x;
  const int c = t & 15, s = t >> 4;
  const int col = blockIdx.x * 16 + c;
  float acc = 0.f;
  for (int ch = s; ch < 256; ch += 16) acc += partial[ch * 2048 + col];
  red[t] = acc;
  __syncthreads();
  for (int st = 8; st > 0; st >>= 1) {
    if (s < st) red[t] += red[t + st * 16];
    __syncthreads();
  }
  if (s == 0) mean[col] = red[c] * (1.0f / 16384.0f);
}

// rough_query[d] = 0.25 * sum_h dot(Wq[h*256+d, :], mean)  — one wave per row
__global__ __launch_bounds__(256) void k_rq(const float* __restrict__ Wq,
                                            const float* __restrict__ mean,
                                            float* __restrict__ rq) {
  const int w = threadIdx.x >> 6, l = threadIdx.x & 63;
  const int row = blockIdx.x * 4 + w;      // 1024 rows
  float s = 0.f;
#pragma unroll
  for (int j = 0; j < 32; j++)
    s = fmaf(Wq[(size_t)row * 2048 + j * 64 + l], mean[j * 64 + l], s);
  for (int mk = 1; mk < 64; mk <<= 1) s += __shfl_xor(s, mk);
  if (l == 0) atomicAdd(&rq[row & 255], 0.25f * s);
}

// ---------- rough scores (one wave per belief; mask layout sniffed inline) ----------
__global__ __launch_bounds__(256) void k_rough(const float* __restrict__ beliefs,
                                               const void* __restrict__ amask,
                                               const float* __restrict__ rq,
                                               u64* __restrict__ keys) {
  const int t = threadIdx.x, w = t >> 6, l = t & 63;
  const int n = blockIdx.x * 4 + w;
  // layout sniff: int32 words of 0/1 vs packed bytes (first 64 words, L2-hot)
  u32 mv = ((const u32*)amask)[l];
  bool isInt = (__ballot(mv > 1u) == 0ull);
  float4 b = *(const float4*)(beliefs + (size_t)n * 256 + l * 4);
  float4 qv = *(const float4*)(rq + l * 4);
  float dot = b.x * qv.x + b.y * qv.y + b.z * qv.z + b.w * qv.w;
  float ss = b.x * b.x + b.y * b.y + b.z * b.z + b.w * b.w;
  for (int mk = 1; mk < 64; mk <<= 1) { dot += __shfl_xor(dot, mk); ss += __shfl_xor(ss, mk); }
  if (l == 0) {
    bool act = isInt ? (((const int*)amask)[n] != 0)
                     : (((const unsigned char*)amask)[n] != 0);
    float score = act ? dot / fmaxf(sqrtf(ss), 1e-8f) : -1e30f;
    keys[n] = packkey(score, (u32)n);
  }
}

// ---------- top-k stage 1: 64 blocks x 1024 keys, register-shuffle selection ----------
__global__ __launch_bounds__(256) void k_top1(const u64* __restrict__ keys,
                                              u64* __restrict__ cands) {
  __shared__ u64 ws[128];
  const int t = threadIdx.x, w = t >> 6, l = t & 63;
  const u64* src = keys + (size_t)blockIdx.x * 1024;
  u64 v0 = src[t], v1 = src[t + 256], v2 = src[t + 512], v3 = src[t + 768];
  for (int r = 0; r < 32; r++) {
    u64 a = v0 > v1 ? v0 : v1;
    u64 b = v2 > v3 ? v2 : v3;
    u64 m = a > b ? a : b;
#pragma unroll
    for (int mk = 1; mk < 64; mk <<= 1) { u64 o = __shfl_xor(m, mk); m = o > m ? o : m; }
    if (l == 0) ws[w * 32 + r] = m;
    v0 = (v0 == m) ? 0ull : v0;
    v1 = (v1 == m) ? 0ull : v1;
    v2 = (v2 == m) ? 0ull : v2;
    v3 = (v3 == m) ? 0ull : v3;
  }
  __syncthreads();
  if (w == 0) {
    u64 u0 = ws[l], u1 = ws[64 + l];
    for (int r = 0; r < 32; r++) {
      u64 m = u0 > u1 ? u0 : u1;
#pragma unroll
      for (int mk = 1; mk < 64; mk <<= 1) { u64 o = __shfl_xor(m, mk); m = o > m ? o : m; }
      if (l == 0) cands[blockIdx.x * 32 + r] = m;
      u0 = (u0 == m) ? 0ull : u0;
      u1 = (u1 == m) ? 0ull : u1;
    }
  }
}

// ---------- top-k stage 2 (2048 cands -> 32) fused with prep ----------
__global__ __launch_bounds__(256) void k_top2_prep(const u64* __restrict__ cands,
                                                   const float* __restrict__ beliefs,
                                                   const float* __restrict__ goals,
                                                   const float* __restrict__ prio,
                                                   const float* __restrict__ logt,
                                                   float* __restrict__ keysf_g,
                                                   float* __restrict__ valsf_g,
                                                   float* __restrict__ biasO,
                                                   float* __restrict__ tempO) {
  __shared__ u64 ws[128];
  __shared__ int idxS[32];
  __shared__ float keysf[32 * 256];
  __shared__ float gradS[16];
  const int t = threadIdx.x, w = t >> 6, l = t & 63;
  // ---- exact top-32 of 2048 candidates, register-shuffle ----
  u64 v[8];
#pragma unroll
  for (int i = 0; i < 8; i++) v[i] = cands[t + i * 256];
  for (int r = 0; r < 32; r++) {
    u64 m = v[0];
#pragma unroll
    for (int i = 1; i < 8; i++) m = v[i] > m ? v[i] : m;
#pragma unroll
    for (int mk = 1; mk < 64; mk <<= 1) { u64 o = __shfl_xor(m, mk); m = o > m ? o : m; }
    if (l == 0) ws[w * 32 + r] = m;
#pragma unroll
    for (int i = 0; i < 8; i++) v[i] = (v[i] == m) ? 0ull : v[i];
  }
  __syncthreads();
  if (w == 0) {
    u64 u0 = ws[l], u1 = ws[64 + l];
    for (int r = 0; r < 32; r++) {
      u64 m = u0 > u1 ? u0 : u1;
#pragma unroll
      for (int mk = 1; mk < 64; mk <<= 1) { u64 o = __shfl_xor(m, mk); m = o > m ? o : m; }
      if (l == 0) idxS[r] = (int)(~(u32)(m & 0xffffffffull));
      u0 = (u0 == m) ? 0ull : u0;
      u1 = (u1 == m) ? 0ull : u1;
    }
  }
  __syncthreads();
  // ---- prep: gather + keys/values/goal-bias/temperature ----
  for (int g = w * 4; g < w * 4 + 4; g++) {
    float4 gv = *(const float4*)(goals + g * 256 + l * 4);
    float ss = gv.x * gv.x + gv.y * gv.y + gv.z * gv.z + gv.w * gv.w;
    for (int mk = 1; mk < 64; mk <<= 1) ss += __shfl_xor(ss, mk);
    if (l == 0) gradS[g] = fmaxf(sqrtf(ss), 1e-8f);
  }
  for (int kk = w * 8; kk < w * 8 + 8; kk++) {
    int idx = idxS[kk];
    float4 bv = *(const float4*)(beliefs + (size_t)idx * 256 + l * 4);
    float ss = bv.x * bv.x + bv.y * bv.y + bv.z * bv.z + bv.w * bv.w;
    for (int mk = 1; mk < 64; mk <<= 1) ss += __shfl_xor(ss, mk);
    float rr = 1.0f / fmaxf(sqrtf(ss), 1e-8f);
    float4 kv; kv.x = bv.x * rr; kv.y = bv.y * rr; kv.z = bv.z * rr; kv.w = bv.w * rr;
    *(float4*)&keysf[kk * 256 + l * 4] = kv;
    *(float4*)&keysf_g[kk * 256 + l * 4] = kv;
    *(float4*)&valsf_g[kk * 256 + l * 4] = bv;
  }
  __syncthreads();
  for (int kk = w * 8; kk < w * 8 + 8; kk++) {
    float4 kv = *(const float4*)&keysf[kk * 256 + l * 4];
    float best = -1e30f;
    for (int g = 0; g < 16; g++) {
      float4 gv = *(const float4*)(goals + g * 256 + l * 4);
      float d = kv.x * gv.x + kv.y * gv.y + kv.z * gv.z + kv.w * gv.w;
      for (int mk = 1; mk < 64; mk <<= 1) d += __shfl_xor(d, mk);
      float sim = d / gradS[g] * prio[g];
      best = fmaxf(best, sim);
    }
    if (l == 0) biasO[kk] = best;
  }
  if (t < 4) tempO[t] = fmaxf(__expf(logt[t]), 0.1f);
}

// ---------- merged K' and VWo^T builds (192 blocks) ----------
__global__ __launch_bounds__(256) void k_build(const float* __restrict__ Wq,
                                               const float* __restrict__ Wo,
                                               const float* __restrict__ keysf_g,
                                               const float* __restrict__ valsf_g,
                                               u16* __restrict__ Kp,
                                               u16* __restrict__ VWoT) {
  __shared__ __align__(16) float sbuf[16384];  // 64 KB, aliased by both halves
  const int t = threadIdx.x;
  if (blockIdx.x < 128) {
    // Kp[h*32+n, c] = sum_d keys[n,d] * Wq[h*256+d, c]
    float* keysS = sbuf;          // 32*256
    float* WqS = sbuf + 8192;     // 64*64
    const int h = blockIdx.x >> 5;
    const int c0 = (blockIdx.x & 31) * 64;
#pragma unroll
    for (int it = 0; it < 32; it++) keysS[t + it * 256] = keysf_g[t + it * 256];
    const int n0 = (t >> 5) * 4;
    const int c2 = (t & 31) * 2;
    float acc[4][2] = {};
    for (int dc = 0; dc < 4; dc++) {
      __syncthreads();
#pragma unroll
      for (int it = 0; it < 16; it++) {
        int i = t + it * 256;
        int r = i >> 6, c = i & 63;
        WqS[i] = Wq[(size_t)(h * 256 + dc * 64 + r) * 2048 + c0 + c];
      }
      __syncthreads();
      for (int d4 = 0; d4 < 16; d4++) {
        float4 kv[4];
#pragma unroll
        for (int i = 0; i < 4; i++)
          kv[i] = *(const float4*)&keysS[(n0 + i) * 256 + dc * 64 + d4 * 4];
#pragma unroll
        for (int dd = 0; dd < 4; dd++) {
          float2 w2 = *(const float2*)&WqS[(d4 * 4 + dd) * 64 + c2];
          float kvd[4] = {kv[0][dd], kv[1][dd], kv[2][dd], kv[3][dd]};
#pragma unroll
          for (int i = 0; i < 4; i++) {
            acc[i][0] = fmaf(kvd[i], w2.x, acc[i][0]);
            acc[i][1] = fmaf(kvd[i], w2.y, acc[i][1]);
          }
        }
      }
    }
#pragma unroll
    for (int i = 0; i < 4; i++) {
      u32 pk = (u32)f2bf(acc[i][0]) | ((u32)f2bf(acc[i][1]) << 16);
      *(u32*)&Kp[(size_t)(h * 32 + n0 + i) * 2048 + c0 + c2] = pk;
    }
  } else {
    // VWoT[c, h*32+n] = sum_d vals[n,d] * Wo[c, h*256+d]
    float* valsS = sbuf;          // 32*256
    float* WoS = sbuf + 8192;     // 32*256
    const int c0 = (blockIdx.x - 128) * 32;
#pragma unroll
    for (int it = 0; it < 32; it++) valsS[t + it * 256] = valsf_g[t + it * 256];
    const int c = t >> 3;
    const int n0 = (t & 7) * 4;
    for (int h = 0; h < 4; h++) {
      __syncthreads();
#pragma unroll
      for (int it = 0; it < 32; it++) {
        int i = t + it * 256;
        int r = i >> 8, d = i & 255;
        WoS[i] = Wo[(size_t)(c0 + r) * 1024 + h * 256 + d];
      }
      __syncthreads();
      float acc[4] = {};
      for (int d4 = 0; d4 < 64; d4++) {
        float4 w4 = *(const float4*)&WoS[c * 256 + d4 * 4];
#pragma unroll
        for (int i = 0; i < 4; i++) {
          float4 kv = *(const float4*)&valsS[(n0 + i) * 256 + d4 * 4];
          acc[i] = fmaf(w4.x, kv.x, acc[i]);
          acc[i] = fmaf(w4.y, kv.y, acc[i]);
          acc[i] = fmaf(w4.z, kv.z, acc[i]);
          acc[i] = fmaf(w4.w, kv.w, acc[i]);
        }
      }
      ushort4 o; o.x = f2bf(acc[0]); o.y = f2bf(acc[1]); o.z = f2bf(acc[2]); o.w = f2bf(acc[3]);
      *(ushort4*)&VWoT[(size_t)(c0 + c) * 128 + h * 32 + n0] = o;
    }
  }
}

// ---------- fused scores -> softmax -> output GEMM (flash-style, pipelined) ----------
// 256 blocks x 512 threads (8 waves). Block = 64 rows of hb.
// Phase 1: S[64][128] = hb_tile @ Kp^T (K=2048, BK=64). Quad-buffered LDS staging,
//   counted vmcnt (prefetch depth 3, loads stay in flight across raw s_barriers).
// Softmax per head within a wave -> P bf16 in swizzled LDS.
// Phase 3: out[64][2048] = P @ VWoT^T, BARRIER-FREE: P frags hoisted to regs (chunk-
//   invariant), V frags streamed from global (L2-hot), stores never drained.
__global__ __launch_bounds__(512) void k_attn(const u16* __restrict__ hb,
                                              const u16* __restrict__ kp,
                                              const u16* __restrict__ vwot,
                                              const float* __restrict__ bias,
                                              const float* __restrict__ temp,
                                              float* __restrict__ out) {
  // LDS: A bufs 4x8KB @ u16 0..16383 | B bufs 4x16KB @ 16384..49151 | P 16KB @ 49152
  __shared__ __align__(16) u16 smem[57344];   // 112 KB
  u16* Plds = smem + 49152;
  const int t = threadIdx.x;
  const int w = t >> 6, l = t & 63;
  const int q = l >> 4, c = l & 15;
  const int m0 = blockIdx.x * 64;
  const int rh = w >> 2, hd = w & 3;

  // ---- preload softmax constants; fence so they don't pollute vmcnt counts ----
  const float ts = temp[hd] * 0.0625f;        // temp/sqrt(256)
  const float b0 = bias[c], b1 = bias[16 + c];
  asm volatile("s_waitcnt vmcnt(0) lgkmcnt(0)" ::: "memory");

  // ---- phase 1 staging addresses (linear LDS dest, inverse-swizzled global src) ----
  const int rowA = t >> 3;                    // 64 rows x 64 bf16 (8 slots of 16B)
  const int cbA = (t & 7) ^ (rowA & 7);
  const u16* srcA = hb + (size_t)(m0 + rowA) * 2048 + cbA * 8;
  const int rowB1 = 64 + rowA;
  const int cbB0 = (t & 7) ^ (rowA & 7);
  const int cbB1 = (t & 7) ^ (rowB1 & 7);
  const u16* srcB0 = kp + (size_t)rowA * 2048 + cbB0 * 8;
  const u16* srcB1 = kp + (size_t)rowB1 * 2048 + cbB1 * 8;
  u16* dstA = smem + w * 512;                 // + buf*4096
  u16* dstB0 = smem + 16384 + w * 512;        // + buf*8192
  u16* dstB1 = smem + 16384 + 4096 + w * 512; // + buf*8192

  auto issue3 = [&](int j) {
    const int bo = j & 3;
    gld_lds16(srcA + j * 64, dstA + bo * 4096);
    gld_lds16(srcB0 + j * 64, dstB0 + bo * 8192);
    gld_lds16(srcB1 + j * 64, dstB1 + bo * 8192);
  };

  f32x4 acc[2][2] = {};
  issue3(0); issue3(1); issue3(2);            // depth-3 prologue (9 ops in flight)

  for (int s = 0; s < 32; s++) {
    // retire loads(s): 6 (or fewer at tail) newer staging ops may stay in flight
    if (s <= 29)      asm volatile("s_waitcnt vmcnt(6)" ::: "memory");
    else if (s == 30) asm volatile("s_waitcnt vmcnt(3)" ::: "memory");
    else              asm volatile("s_waitcnt vmcnt(0)" ::: "memory");
    __builtin_amdgcn_s_barrier();             // all waves' loads(s) landed; reads(s-1) done
    __builtin_amdgcn_sched_barrier(0);
    if (s < 29) issue3(s + 3);                // safe: buf[(s+3)&3] fully read at iter s-1

    const u16* Ab = smem + (s & 3) * 4096;
    const u16* Bb = smem + 16384 + (s & 3) * 8192;
    bf16x8 af[2][2], bfr[2][2];
#pragma unroll
    for (int mi = 0; mi < 2; mi++) {
      const int ra = rh * 32 + mi * 16 + c;
#pragma unroll
      for (int ks = 0; ks < 2; ks++)
        af[mi][ks] = __builtin_bit_cast(bf16x8,
            *(const uint4*)&Ab[ra * 64 + (((ks * 4 + q) ^ (ra & 7)) * 8)]);
    }
#pragma unroll
    for (int ni = 0; ni < 2; ni++) {
      const int rb = hd * 32 + ni * 16 + c;
#pragma unroll
      for (int ks = 0; ks < 2; ks++)
        bfr[ni][ks] = __builtin_bit_cast(bf16x8,
            *(const uint4*)&Bb[rb * 64 + (((ks * 4 + q) ^ (rb & 7)) * 8)]);
    }
    asm volatile("s_waitcnt lgkmcnt(0)" ::: "memory");
    __builtin_amdgcn_sched_barrier(0);
#pragma unroll
    for (int ks = 0; ks < 2; ks++)
#pragma unroll
      for (int mi = 0; mi < 2; mi++)
#pragma unroll
        for (int ni = 0; ni < 2; ni++)
          acc[mi][ni] = __builtin_amdgcn_mfma_f32_16x16x32_bf16(af[mi][ks], bfr[ni][ks],
                                                                acc[mi][ni], 0, 0, 0);
  }

  // ---- softmax per head (within wave), write P bf16 to swizzled LDS ----
#pragma unroll
  for (int mi = 0; mi < 2; mi++) {
#pragma unroll
    for (int r = 0; r < 4; r++) {
      float v0 = fmaf(acc[mi][0][r], ts, b0);
      float v1 = fmaf(acc[mi][1][r], ts, b1);
      float m = fmaxf(v0, v1);
#pragma unroll
      for (int mk = 1; mk <= 8; mk <<= 1) m = fmaxf(m, __shfl_xor(m, mk));
      float e0 = __expf(v0 - m), e1 = __expf(v1 - m);
      float sum = e0 + e1;
#pragma unroll
      for (int mk = 1; mk <= 8; mk <<= 1) sum += __shfl_xor(sum, mk);
      float inv = 1.0f / sum;
      const int rp = rh * 32 + mi * 16 + q * 4 + r;
      const int k0 = hd * 32 + c, k1 = k0 + 16;
      Plds[rp * 128 + (((k0 >> 3) ^ (rp & 7)) * 8) + (k0 & 7)] = f2bf(e0 * inv);
      Plds[rp * 128 + (((k1 >> 3) ^ (rp & 7)) * 8) + (k1 & 7)] = f2bf(e1 * inv);
    }
  }
  __syncthreads();   // P visible to all waves (full drain OK, once)

  // ---- phase 3: out = P @ VWoT^T, barrier-free, V streamed from global ----
  const int rw = w & 3, chh = w >> 2;
  const int rp = rw * 16 + c;
  bf16x8 pa[4];
#pragma unroll
  for (int ks = 0; ks < 4; ks++)
    pa[ks] = __builtin_bit_cast(bf16x8,
        *(const uint4*)&Plds[rp * 128 + (((ks * 4 + q) ^ (rp & 7)) * 8)]);

  for (int cb = 0; cb < 32; cb++) {
    f32x4 oacc[2] = {};
#pragma unroll
    for (int ni = 0; ni < 2; ni++) {
      const int rv = cb * 64 + chh * 32 + ni * 16 + c;
      const u16* vr = vwot + (size_t)rv * 128 + q * 8;
#pragma unroll
      for (int ks = 0; ks < 4; ks++) {
        bf16x8 vb = __builtin_bit_cast(bf16x8, *(const uint4*)(vr + ks * 32));
        oacc[ni] = __builtin_amdgcn_mfma_f32_16x16x32_bf16(pa[ks], vb, oacc[ni], 0, 0, 0);
      }
    }
#pragma unroll
    for (int ni = 0; ni < 2; ni++) {
      const int col = cb * 64 + chh * 32 + ni * 16 + c;
#pragma unroll
      for (int r = 0; r < 4; r++)
        out[(size_t)(m0 + rw * 16 + q * 4 + r) * 2048 + col] = oacc[ni][r];
    }
  }
}

// ---------- launch ----------
extern "C" void kernel_launch(void* const* d_in, const int* in_sizes, int n_in,
                              void* d_out, int out_size, void* d_ws, size_t ws_size,
                              hipStream_t stream) {
  const float* hidden = (const float*)d_in[0];
  const float* beliefs = (const float*)d_in[1];
  const void* amask = d_in[2];
  const float* goals = (const float*)d_in[3];
  const float* prio = (const float*)d_in[4];
  const float* Wq = (const float*)d_in[5];
  const float* Wo = (const float*)d_in[6];
  const float* logt = (const float*)d_in[7];
  float* out = (float*)d_out;

  char* ws = (char*)d_ws;
  size_t off = 0;
  auto alloc = [&](size_t bytes) { char* p = ws + off; off = (off + bytes + 255) & ~(size_t)255; return p; };
  u16* hb      = (u16*)alloc(67108864);    // hidden bf16
  u16* kp      = (u16*)alloc(524288);      // K' [128 x 2048] bf16
  u16* vwot    = (u16*)alloc(524288);      // VWo^T [2048 x 128] bf16
  float* partial = (float*)alloc(2097152); // 256 chunks x 2048 cols
  float* meanq = (float*)alloc(8192);
  float* rq    = (float*)alloc(1024);
  u64* keys    = (u64*)alloc(524288);
  u64* cands   = (u64*)alloc(16384);
  float* keysf = (float*)alloc(32768);
  float* valsf = (float*)alloc(32768);
  float* biasv = (float*)alloc(128);
  float* tempv = (float*)alloc(16);

  hipMemsetAsync(rq, 0, 1024, stream);
  k_conv_mean<<<dim3(2, 256), 256, 0, stream>>>((const float4*)hidden, (ushort4*)hb, (float4*)partial);
  k_mean<<<128, 256, 0, stream>>>(partial, meanq);
  k_rq<<<256, 256, 0, stream>>>(Wq, meanq, rq);
  k_rough<<<16384, 256, 0, stream>>>(beliefs, amask, rq, keys);
  k_top1<<<64, 256, 0, stream>>>(keys, cands);
  k_top2_prep<<<1, 256, 0, stream>>>(cands, beliefs, goals, prio, logt, keysf, valsf, biasv, tempv);
  k_build<<<192, 256, 0, stream>>>(Wq, Wo, keysf, valsf, kp, vwot);
  k_attn<<<256, 512, 0, stream>>>(hb, kp, vwot, biasv, tempv, out);
}

// Round 3
// 505.225 us; speedup vs baseline: 1.0447x; 1.0447x over previous
//
#include <hip/hip_runtime.h>

typedef unsigned int u32;
typedef unsigned short u16;
typedef unsigned long long u64;

typedef __bf16 bf16x8 __attribute__((ext_vector_type(8)));
typedef float f32x4 __attribute__((ext_vector_type(4)));

#define DEV __device__ __forceinline__

// ---------- helpers ----------
DEV u16 f2bf(float f) {            // RNE float -> bf16
  u32 u = __float_as_uint(f);
  u += 0x7fffu + ((u >> 16) & 1u);
  return (u16)(u >> 16);
}
DEV float bf2f(u16 u) { return __uint_as_float((u32)u << 16); }

DEV void gld_lds16(const void* g, void* l) {
  __builtin_amdgcn_global_load_lds((const __attribute__((address_space(1))) u32*)g,
                                   (__attribute__((address_space(3))) u32*)l, 16, 0, 0);
}

// monotone (value, lower-index-wins) packed sort key
DEV u64 packkey(float f, u32 idx) {
  u32 u = __float_as_uint(f);
  u = (u & 0x80000000u) ? ~u : (u | 0x80000000u);
  return ((u64)u << 32) | (u32)(~idx);
}

// ---------- hidden -> bf16 + column partial sums (float4, 512 blocks) ----------
__global__ __launch_bounds__(256) void k_conv_mean(const float4* __restrict__ hidden4,
                                                   ushort4* __restrict__ hb4,
                                                   float4* __restrict__ partial4) {
  const int c4 = blockIdx.x * 256 + threadIdx.x;   // 0..511
  const int r0 = blockIdx.y * 64;                  // 256 row-chunks
  float4 s = {0.f, 0.f, 0.f, 0.f};
  for (int r = 0; r < 64; r++) {
    float4 v = hidden4[(size_t)(r0 + r) * 512 + c4];
    ushort4 o; o.x = f2bf(v.x); o.y = f2bf(v.y); o.z = f2bf(v.z); o.w = f2bf(v.w);
    hb4[(size_t)(r0 + r) * 512 + c4] = o;
    s.x += v.x; s.y += v.y; s.z += v.z; s.w += v.w;
  }
  partial4[blockIdx.y * 512 + c4] = s;
}

// reduce 256 chunks -> mean (128 blocks, 16 cols each, 16-way split per col)
__global__ __launch_bounds__(256) void k_mean(const float* __restrict__ partial,
                                              float* __restrict__ mean) {
  __shared__ float red[256];
  const int t = threadIdx.x;
  const int c = t & 15, s = t >> 4;
  const int col = blockIdx.x * 16 + c;
  float acc = 0.f;
  for (int ch = s; ch < 256; ch += 16) acc += partial[ch * 2048 + col];
  red[t] = acc;
  __syncthreads();
  for (int st = 8; st > 0; st >>= 1) {
    if (s < st) red[t] += red[t + st * 16];
    __syncthreads();
  }
  if (s == 0) mean[col] = red[c] * (1.0f / 16384.0f);
}

// rough_query[d] = 0.25 * sum_h dot(Wq[h*256+d, :], mean)  — one wave per row
__global__ __launch_bounds__(256) void k_rq(const float* __restrict__ Wq,
                                            const float* __restrict__ mean,
                                            float* __restrict__ rq) {
  const int w = threadIdx.x >> 6, l = threadIdx.x & 63;
  const int row = blockIdx.x * 4 + w;      // 1024 rows
  float s = 0.f;
#pragma unroll
  for (int j = 0; j < 32; j++)
    s = fmaf(Wq[(size_t)row * 2048 + j * 64 + l], mean[j * 64 + l], s);
  for (int mk = 1; mk < 64; mk <<= 1) s += __shfl_xor(s, mk);
  if (l == 0) atomicAdd(&rq[row & 255], 0.25f * s);
}

// ---------- rough scores (one wave per belief; mask layout sniffed inline) ----------
__global__ __launch_bounds__(256) void k_rough(const float* __restrict__ beliefs,
                                               const void* __restrict__ amask,
                                               const float* __restrict__ rq,
                                               u64* __restrict__ keys) {
  const int t = threadIdx.x, w = t >> 6, l = t & 63;
  const int n = blockIdx.x * 4 + w;
  // layout sniff: int32 words of 0/1 vs packed bytes (first 64 words, L2-hot)
  u32 mv = ((const u32*)amask)[l];
  bool isInt = (__ballot(mv > 1u) == 0ull);
  float4 b = *(const float4*)(beliefs + (size_t)n * 256 + l * 4);
  float4 qv = *(const float4*)(rq + l * 4);
  float dot = b.x * qv.x + b.y * qv.y + b.z * qv.z + b.w * qv.w;
  float ss = b.x * b.x + b.y * b.y + b.z * b.z + b.w * b.w;
  for (int mk = 1; mk < 64; mk <<= 1) { dot += __shfl_xor(dot, mk); ss += __shfl_xor(ss, mk); }
  if (l == 0) {
    bool act = isInt ? (((const int*)amask)[n] != 0)
                     : (((const unsigned char*)amask)[n] != 0);
    float score = act ? dot / fmaxf(sqrtf(ss), 1e-8f) : -1e30f;
    keys[n] = packkey(score, (u32)n);
  }
}

// ---------- top-k stage 1: 64 blocks x 1024 keys, register-shuffle selection ----------
__global__ __launch_bounds__(256) void k_top1(const u64* __restrict__ keys,
                                              u64* __restrict__ cands) {
  __shared__ u64 ws[128];
  const int t = threadIdx.x, w = t >> 6, l = t & 63;
  const u64* src = keys + (size_t)blockIdx.x * 1024;
  u64 v0 = src[t], v1 = src[t + 256], v2 = src[t + 512], v3 = src[t + 768];
  for (int r = 0; r < 32; r++) {
    u64 a = v0 > v1 ? v0 : v1;
    u64 b = v2 > v3 ? v2 : v3;
    u64 m = a > b ? a : b;
#pragma unroll
    for (int mk = 1; mk < 64; mk <<= 1) { u64 o = __shfl_xor(m, mk); m = o > m ? o : m; }
    if (l == 0) ws[w * 32 + r] = m;
    v0 = (v0 == m) ? 0ull : v0;
    v1 = (v1 == m) ? 0ull : v1;
    v2 = (v2 == m) ? 0ull : v2;
    v3 = (v3 == m) ? 0ull : v3;
  }
  __syncthreads();
  if (w == 0) {
    u64 u0 = ws[l], u1 = ws[64 + l];
    for (int r = 0; r < 32; r++) {
      u64 m = u0 > u1 ? u0 : u1;
#pragma unroll
      for (int mk = 1; mk < 64; mk <<= 1) { u64 o = __shfl_xor(m, mk); m = o > m ? o : m; }
      if (l == 0) cands[blockIdx.x * 32 + r] = m;
      u0 = (u0 == m) ? 0ull : u0;
      u1 = (u1 == m) ? 0ull : u1;
    }
  }
}

// ---------- top-k stage 2 (2048 cands -> 32) fused with prep ----------
__global__ __launch_bounds__(256) void k_top2_prep(const u64* __restrict__ cands,
                                                   const float* __restrict__ beliefs,
                                                   const float* __restrict__ goals,
                                                   const float* __restrict__ prio,
                                                   const float* __restrict__ logt,
                                                   float* __restrict__ keysf_g,
                                                   float* __restrict__ valsf_g,
                                                   float* __restrict__ biasO,
                                                   float* __restrict__ tempO) {
  __shared__ u64 ws[128];
  __shared__ int idxS[32];
  __shared__ float keysf[32 * 256];
  __shared__ float gradS[16];
  const int t = threadIdx.x, w = t >> 6, l = t & 63;
  // ---- exact top-32 of 2048 candidates, register-shuffle ----
  u64 v[8];
#pragma unroll
  for (int i = 0; i < 8; i++) v[i] = cands[t + i * 256];
  for (int r = 0; r < 32; r++) {
    u64 m = v[0];
#pragma unroll
    for (int i = 1; i < 8; i++) m = v[i] > m ? v[i] : m;
#pragma unroll
    for (int mk = 1; mk < 64; mk <<= 1) { u64 o = __shfl_xor(m, mk); m = o > m ? o : m; }
    if (l == 0) ws[w * 32 + r] = m;
#pragma unroll
    for (int i = 0; i < 8; i++) v[i] = (v[i] == m) ? 0ull : v[i];
  }
  __syncthreads();
  if (w == 0) {
    u64 u0 = ws[l], u1 = ws[64 + l];
    for (int r = 0; r < 32; r++) {
      u64 m = u0 > u1 ? u0 : u1;
#pragma unroll
      for (int mk = 1; mk < 64; mk <<= 1) { u64 o = __shfl_xor(m, mk); m = o > m ? o : m; }
      if (l == 0) idxS[r] = (int)(~(u32)(m & 0xffffffffull));
      u0 = (u0 == m) ? 0ull : u0;
      u1 = (u1 == m) ? 0ull : u1;
    }
  }
  __syncthreads();
  // ---- prep: gather + keys/values/goal-bias/temperature ----
  for (int g = w * 4; g < w * 4 + 4; g++) {
    float4 gv = *(const float4*)(goals + g * 256 + l * 4);
    float ss = gv.x * gv.x + gv.y * gv.y + gv.z * gv.z + gv.w * gv.w;
    for (int mk = 1; mk < 64; mk <<= 1) ss += __shfl_xor(ss, mk);
    if (l == 0) gradS[g] = fmaxf(sqrtf(ss), 1e-8f);
  }
  for (int kk = w * 8; kk < w * 8 + 8; kk++) {
    int idx = idxS[kk];
    float4 bv = *(const float4*)(beliefs + (size_t)idx * 256 + l * 4);
    float ss = bv.x * bv.x + bv.y * bv.y + bv.z * bv.z + bv.w * bv.w;
    for (int mk = 1; mk < 64; mk <<= 1) ss += __shfl_xor(ss, mk);
    float rr = 1.0f / fmaxf(sqrtf(ss), 1e-8f);
    float4 kv; kv.x = bv.x * rr; kv.y = bv.y * rr; kv.z = bv.z * rr; kv.w = bv.w * rr;
    *(float4*)&keysf[kk * 256 + l * 4] = kv;
    *(float4*)&keysf_g[kk * 256 + l * 4] = kv;
    *(float4*)&valsf_g[kk * 256 + l * 4] = bv;
  }
  __syncthreads();
  for (int kk = w * 8; kk < w * 8 + 8; kk++) {
    float4 kv = *(const float4*)&keysf[kk * 256 + l * 4];
    float best = -1e30f;
    for (int g = 0; g < 16; g++) {
      float4 gv = *(const float4*)(goals + g * 256 + l * 4);
      float d = kv.x * gv.x + kv.y * gv.y + kv.z * gv.z + kv.w * gv.w;
      for (int mk = 1; mk < 64; mk <<= 1) d += __shfl_xor(d, mk);
      float sim = d / gradS[g] * prio[g];
      best = fmaxf(best, sim);
    }
    if (l == 0) biasO[kk] = best;
  }
  if (t < 4) tempO[t] = fmaxf(__expf(logt[t]), 0.1f);
}

// ---------- merged K' and VWo^T builds (192 blocks) ----------
__global__ __launch_bounds__(256) void k_build(const float* __restrict__ Wq,
                                               const float* __restrict__ Wo,
                                               const float* __restrict__ keysf_g,
                                               const float* __restrict__ valsf_g,
                                               u16* __restrict__ Kp,
                                               u16* __restrict__ VWoT) {
  __shared__ __align__(16) float sbuf[16384];  // 64 KB, aliased by both halves
  const int t = threadIdx.x;
  if (blockIdx.x < 128) {
    // Kp[h*32+n, c] = sum_d keys[n,d] * Wq[h*256+d, c]
    float* keysS = sbuf;          // 32*256
    float* WqS = sbuf + 8192;     // 64*64
    const int h = blockIdx.x >> 5;
    const int c0 = (blockIdx.x & 31) * 64;
#pragma unroll
    for (int it = 0; it < 32; it++) keysS[t + it * 256] = keysf_g[t + it * 256];
    const int n0 = (t >> 5) * 4;
    const int c2 = (t & 31) * 2;
    float acc[4][2] = {};
    for (int dc = 0; dc < 4; dc++) {
      __syncthreads();
#pragma unroll
      for (int it = 0; it < 16; it++) {
        int i = t + it * 256;
        int r = i >> 6, c = i & 63;
        WqS[i] = Wq[(size_t)(h * 256 + dc * 64 + r) * 2048 + c0 + c];
      }
      __syncthreads();
      for (int d4 = 0; d4 < 16; d4++) {
        float4 kv[4];
#pragma unroll
        for (int i = 0; i < 4; i++)
          kv[i] = *(const float4*)&keysS[(n0 + i) * 256 + dc * 64 + d4 * 4];
#pragma unroll
        for (int dd = 0; dd < 4; dd++) {
          float2 w2 = *(const float2*)&WqS[(d4 * 4 + dd) * 64 + c2];
          float kvd[4] = {kv[0][dd], kv[1][dd], kv[2][dd], kv[3][dd]};
#pragma unroll
          for (int i = 0; i < 4; i++) {
            acc[i][0] = fmaf(kvd[i], w2.x, acc[i][0]);
            acc[i][1] = fmaf(kvd[i], w2.y, acc[i][1]);
          }
        }
      }
    }
#pragma unroll
    for (int i = 0; i < 4; i++) {
      u32 pk = (u32)f2bf(acc[i][0]) | ((u32)f2bf(acc[i][1]) << 16);
      *(u32*)&Kp[(size_t)(h * 32 + n0 + i) * 2048 + c0 + c2] = pk;
    }
  } else {
    // VWoT[c, h*32+n] = sum_d vals[n,d] * Wo[c, h*256+d]
    float* valsS = sbuf;          // 32*256
    float* WoS = sbuf + 8192;     // 32*256
    const int c0 = (blockIdx.x - 128) * 32;
#pragma unroll
    for (int it = 0; it < 32; it++) valsS[t + it * 256] = valsf_g[t + it * 256];
    const int c = t >> 3;
    const int n0 = (t & 7) * 4;
    for (int h = 0; h < 4; h++) {
      __syncthreads();
#pragma unroll
      for (int it = 0; it < 32; it++) {
        int i = t + it * 256;
        int r = i >> 8, d = i & 255;
        WoS[i] = Wo[(size_t)(c0 + r) * 1024 + h * 256 + d];
      }
      __syncthreads();
      float acc[4] = {};
      for (int d4 = 0; d4 < 64; d4++) {
        float4 w4 = *(const float4*)&WoS[c * 256 + d4 * 4];
#pragma unroll
        for (int i = 0; i < 4; i++) {
          float4 kv = *(const float4*)&valsS[(n0 + i) * 256 + d4 * 4];
          acc[i] = fmaf(w4.x, kv.x, acc[i]);
          acc[i] = fmaf(w4.y, kv.y, acc[i]);
          acc[i] = fmaf(w4.z, kv.z, acc[i]);
          acc[i] = fmaf(w4.w, kv.w, acc[i]);
        }
      }
      ushort4 o; o.x = f2bf(acc[0]); o.y = f2bf(acc[1]); o.z = f2bf(acc[2]); o.w = f2bf(acc[3]);
      *(ushort4*)&VWoT[(size_t)(c0 + c) * 128 + h * 32 + n0] = o;
    }
  }
}

// ---------- fused scores -> softmax -> output GEMM (flash-style, pipelined) ----------
// 256 blocks x 512 threads (8 waves). Block = 64 rows of hb.
// Phase 1: S[64][128] = hb_tile @ Kp^T (K=2048, BK=64). Quad-buffered LDS staging,
//   counted vmcnt (prefetch depth 3, loads stay in flight across raw s_barriers).
// Softmax per head within a wave -> P bf16 in swizzled LDS.
// Phase 3: out[64][2048] = P @ VWoT^T, barrier-free. Each wave owns a PRIVATE
//   256-col slab (disjoint vwot rows -> minimal L2 traffic, no LDS staging);
//   all 16 P fragments hoisted to registers from LDS once.
__global__ __launch_bounds__(512) void k_attn(const u16* __restrict__ hb,
                                              const u16* __restrict__ kp,
                                              const u16* __restrict__ vwot,
                                              const float* __restrict__ bias,
                                              const float* __restrict__ temp,
                                              float* __restrict__ out) {
  // LDS: A bufs 4x8KB @ u16 0..16383 | B bufs 4x16KB @ 16384..49151 | P 16KB @ 49152
  __shared__ __align__(16) u16 smem[57344];   // 112 KB
  u16* Plds = smem + 49152;
  const int t = threadIdx.x;
  const int w = t >> 6, l = t & 63;
  const int q = l >> 4, c = l & 15;
  const int m0 = blockIdx.x * 64;
  const int rh = w >> 2, hd = w & 3;

  // ---- preload softmax constants; fence so they don't pollute vmcnt counts ----
  const float ts = temp[hd] * 0.0625f;        // temp/sqrt(256)
  const float b0 = bias[c], b1 = bias[16 + c];
  asm volatile("s_waitcnt vmcnt(0) lgkmcnt(0)" ::: "memory");

  // ---- phase 1 staging addresses (linear LDS dest, inverse-swizzled global src) ----
  const int rowA = t >> 3;                    // 64 rows x 64 bf16 (8 slots of 16B)
  const int cbA = (t & 7) ^ (rowA & 7);
  const u16* srcA = hb + (size_t)(m0 + rowA) * 2048 + cbA * 8;
  const int rowB1 = 64 + rowA;
  const int cbB0 = (t & 7) ^ (rowA & 7);
  const int cbB1 = (t & 7) ^ (rowB1 & 7);
  const u16* srcB0 = kp + (size_t)rowA * 2048 + cbB0 * 8;
  const u16* srcB1 = kp + (size_t)rowB1 * 2048 + cbB1 * 8;
  u16* dstA = smem + w * 512;                 // + buf*4096
  u16* dstB0 = smem + 16384 + w * 512;        // + buf*8192
  u16* dstB1 = smem + 16384 + 4096 + w * 512; // + buf*8192

  auto issue3 = [&](int j) {
    const int bo = j & 3;
    gld_lds16(srcA + j * 64, dstA + bo * 4096);
    gld_lds16(srcB0 + j * 64, dstB0 + bo * 8192);
    gld_lds16(srcB1 + j * 64, dstB1 + bo * 8192);
  };

  f32x4 acc[2][2] = {};
  issue3(0); issue3(1); issue3(2);            // depth-3 prologue (9 ops in flight)

  for (int s = 0; s < 32; s++) {
    // retire loads(s): 6 (or fewer at tail) newer staging ops may stay in flight
    if (s <= 29)      asm volatile("s_waitcnt vmcnt(6)" ::: "memory");
    else if (s == 30) asm volatile("s_waitcnt vmcnt(3)" ::: "memory");
    else              asm volatile("s_waitcnt vmcnt(0)" ::: "memory");
    __builtin_amdgcn_s_barrier();             // all waves' loads(s) landed; reads(s-1) done
    __builtin_amdgcn_sched_barrier(0);
    if (s < 29) issue3(s + 3);                // safe: buf[(s+3)&3] fully read at iter s-1

    const u16* Ab = smem + (s & 3) * 4096;
    const u16* Bb = smem + 16384 + (s & 3) * 8192;
    bf16x8 af[2][2], bfr[2][2];
#pragma unroll
    for (int mi = 0; mi < 2; mi++) {
      const int ra = rh * 32 + mi * 16 + c;
#pragma unroll
      for (int ks = 0; ks < 2; ks++)
        af[mi][ks] = __builtin_bit_cast(bf16x8,
            *(const uint4*)&Ab[ra * 64 + (((ks * 4 + q) ^ (ra & 7)) * 8)]);
    }
#pragma unroll
    for (int ni = 0; ni < 2; ni++) {
      const int rb = hd * 32 + ni * 16 + c;
#pragma unroll
      for (int ks = 0; ks < 2; ks++)
        bfr[ni][ks] = __builtin_bit_cast(bf16x8,
            *(const uint4*)&Bb[rb * 64 + (((ks * 4 + q) ^ (rb & 7)) * 8)]);
    }
    asm volatile("s_waitcnt lgkmcnt(0)" ::: "memory");
    __builtin_amdgcn_sched_barrier(0);
#pragma unroll
    for (int ks = 0; ks < 2; ks++)
#pragma unroll
      for (int mi = 0; mi < 2; mi++)
#pragma unroll
        for (int ni = 0; ni < 2; ni++)
          acc[mi][ni] = __builtin_amdgcn_mfma_f32_16x16x32_bf16(af[mi][ks], bfr[ni][ks],
                                                                acc[mi][ni], 0, 0, 0);
  }

  // ---- softmax per head (within wave), write P bf16 to swizzled LDS ----
#pragma unroll
  for (int mi = 0; mi < 2; mi++) {
#pragma unroll
    for (int r = 0; r < 4; r++) {
      float v0 = fmaf(acc[mi][0][r], ts, b0);
      float v1 = fmaf(acc[mi][1][r], ts, b1);
      float m = fmaxf(v0, v1);
#pragma unroll
      for (int mk = 1; mk <= 8; mk <<= 1) m = fmaxf(m, __shfl_xor(m, mk));
      float e0 = __expf(v0 - m), e1 = __expf(v1 - m);
      float sum = e0 + e1;
#pragma unroll
      for (int mk = 1; mk <= 8; mk <<= 1) sum += __shfl_xor(sum, mk);
      float inv = 1.0f / sum;
      const int rp = rh * 32 + mi * 16 + q * 4 + r;
      const int k0 = hd * 32 + c, k1 = k0 + 16;
      Plds[rp * 128 + (((k0 >> 3) ^ (rp & 7)) * 8) + (k0 & 7)] = f2bf(e0 * inv);
      Plds[rp * 128 + (((k1 >> 3) ^ (rp & 7)) * 8) + (k1 & 7)] = f2bf(e1 * inv);
    }
  }
  __syncthreads();   // P visible to all waves (full drain OK, once)

  // ---- phase 3: out = P @ VWoT^T, barrier-free, per-wave 256-col slab ----
  // wave w owns out cols [w*256, w*256+256): disjoint vwot rows across waves.
  const int col0 = w * 256;
  bf16x8 pa[4][4];                            // all 64 P-rows x K=128, 64 VGPRs
#pragma unroll
  for (int mi = 0; mi < 4; mi++) {
    const int rp = mi * 16 + c;
#pragma unroll
    for (int ks = 0; ks < 4; ks++)
      pa[mi][ks] = __builtin_bit_cast(bf16x8,
          *(const uint4*)&Plds[rp * 128 + (((ks * 4 + q) ^ (rp & 7)) * 8)]);
  }
#pragma unroll
  for (int ni = 0; ni < 16; ni++) {
    const int rv = col0 + ni * 16 + c;
    const u16* vr = vwot + (size_t)rv * 128 + q * 8;
    bf16x8 vb[4];
#pragma unroll
    for (int ks = 0; ks < 4; ks++)
      vb[ks] = __builtin_bit_cast(bf16x8, *(const uint4*)(vr + ks * 32));
    f32x4 oacc[4] = {};
#pragma unroll
    for (int mi = 0; mi < 4; mi++)
#pragma unroll
      for (int ks = 0; ks < 4; ks++)
        oacc[mi] = __builtin_amdgcn_mfma_f32_16x16x32_bf16(pa[mi][ks], vb[ks], oacc[mi], 0, 0, 0);
    const int col = col0 + ni * 16 + c;
#pragma unroll
    for (int mi = 0; mi < 4; mi++)
#pragma unroll
      for (int r = 0; r < 4; r++)
        out[(size_t)(m0 + mi * 16 + q * 4 + r) * 2048 + col] = oacc[mi][r];
  }
}

// ---------- launch ----------
extern "C" void kernel_launch(void* const* d_in, const int* in_sizes, int n_in,
                              void* d_out, int out_size, void* d_ws, size_t ws_size,
                              hipStream_t stream) {
  const float* hidden = (const float*)d_in[0];
  const float* beliefs = (const float*)d_in[1];
  const void* amask = d_in[2];
  const float* goals = (const float*)d_in[3];
  const float* prio = (const float*)d_in[4];
  const float* Wq = (const float*)d_in[5];
  const float* Wo = (const float*)d_in[6];
  const float* logt = (const float*)d_in[7];
  float* out = (float*)d_out;

  char* ws = (char*)d_ws;
  size_t off = 0;
  auto alloc = [&](size_t bytes) { char* p = ws + off; off = (off + bytes + 255) & ~(size_t)255; return p; };
  u16* hb      = (u16*)alloc(67108864);    // hidden bf16
  u16* kp      = (u16*)alloc(524288);      // K' [128 x 2048] bf16
  u16* vwot    = (u16*)alloc(524288);      // VWo^T [2048 x 128] bf16
  float* partial = (float*)alloc(2097152); // 256 chunks x 2048 cols
  float* meanq = (float*)alloc(8192);
  float* rq    = (float*)alloc(1024);
  u64* keys    = (u64*)alloc(524288);
  u64* cands   = (u64*)alloc(16384);
  float* keysf = (float*)alloc(32768);
  float* valsf = (float*)alloc(32768);
  float* biasv = (float*)alloc(128);
  float* tempv = (float*)alloc(16);

  hipMemsetAsync(rq, 0, 1024, stream);
  k_conv_mean<<<dim3(2, 256), 256, 0, stream>>>((const float4*)hidden, (ushort4*)hb, (float4*)partial);
  k_mean<<<128, 256, 0, stream>>>(partial, meanq);
  k_rq<<<256, 256, 0, stream>>>(Wq, meanq, rq);
  k_rough<<<16384, 256, 0, stream>>>(beliefs, amask, rq, keys);
  k_top1<<<64, 256, 0, stream>>>(keys, cands);
  k_top2_prep<<<1, 256, 0, stream>>>(cands, beliefs, goals, prio, logt, keysf, valsf, biasv, tempv);
  k_build<<<192, 256, 0, stream>>>(Wq, Wo, keysf, valsf, kp, vwot);
  k_attn<<<256, 512, 0, stream>>>(hb, kp, vwot, biasv, tempv, out);
}